// Round 4
// baseline (624.435 us; speedup 1.0000x reference)
//
#include <hip/hip_runtime.h>
#include <math.h>

// Problem constants: B=1, CQ=8, CV=64, H=W=D=64, fp32.
#define SQC 262144   // channel stride = 64*64*64
#define SH  4096     // h stride = 64*64
#define SW  64       // w stride

// ---------------------------------------------------------------------------
// K1: per-query softmax stats (m = max over 192 energies, rl = 1/sum(exp)).
// Block = one (h,w) line (64 d-queries), 3 waves: wave 0 -> H axis,
// wave 1 -> W axis, wave 2 -> D axis. Per-axis online (m,l) combined in LDS.
// All scalar components of addresses forced into SGPRs via readfirstlane so
// loads are s_base + d*4 (no per-load vector 64-bit address arithmetic).
// ---------------------------------------------------------------------------
__global__ __launch_bounds__(192, 7) void k_stats(
    const float* __restrict__ Q, const float* __restrict__ K,
    float* __restrict__ m_ws, float* __restrict__ rl_ws)
{
    const int tid  = threadIdx.x;
    const int d    = tid & 63;
    const int axis = __builtin_amdgcn_readfirstlane(tid >> 6);  // 0,1,2 wave-uniform
    const int h    = blockIdx.x >> 6;        // SGPR already
    const int w    = blockIdx.x & 63;

    float q[8];
#pragma unroll
    for (int c = 0; c < 8; ++c) q[c] = Q[c * SQC + h * SH + w * SW + d];

    float m = -INFINITY, l = 0.f;

    if (axis == 0) {
        // ---- H axis: keys at (c, x, w, d), mask x==h (wave-uniform) ----
#pragma unroll 1
        for (int xc = 0; xc < 8; ++xc) {
            float e[8];
#pragma unroll
            for (int xi = 0; xi < 8; ++xi) {
                const int x = xc * 8 + xi;
                float a = 0.f;
#pragma unroll
                for (int c = 0; c < 8; ++c)
                    a = fmaf(q[c], K[c * SQC + x * SH + w * SW + d], a);
                e[xi] = (x == h) ? -INFINITY : a;
            }
            float cm = e[0];
#pragma unroll
            for (int xi = 1; xi < 8; ++xi) cm = fmaxf(cm, e[xi]);
            const float nm = fmaxf(m, cm);
            float s = 0.f;
#pragma unroll
            for (int xi = 0; xi < 8; ++xi) s += __expf(e[xi] - nm);
            l = fmaf(l, __expf(m - nm), s);
            m = nm;
        }
    } else if (axis == 1) {
        // ---- W axis: keys at (c, h, y, d), no mask ----
#pragma unroll 1
        for (int yc = 0; yc < 8; ++yc) {
            float e[8];
#pragma unroll
            for (int yi = 0; yi < 8; ++yi) {
                const int y = yc * 8 + yi;
                float a = 0.f;
#pragma unroll
                for (int c = 0; c < 8; ++c)
                    a = fmaf(q[c], K[c * SQC + h * SH + y * SW + d], a);
                e[yi] = a;
            }
            float cm = e[0];
#pragma unroll
            for (int yi = 1; yi < 8; ++yi) cm = fmaxf(cm, e[yi]);
            const float nm = fmaxf(m, cm);
            float s = 0.f;
#pragma unroll
            for (int yi = 0; yi < 8; ++yi) s += __expf(e[yi] - nm);
            l = fmaf(l, __expf(m - nm), s);
            m = nm;
        }
    } else {
        // ---- D axis: keys at (c, h, w, z), mask z==d (per-lane, via -inf) ----
        // All key addresses fully wave-uniform -> scalar loads.
#pragma unroll 1
        for (int zc = 0; zc < 8; ++zc) {
            float e[8];
#pragma unroll
            for (int zi = 0; zi < 8; ++zi) {
                const int z = zc * 8 + zi;
                float a = 0.f;
#pragma unroll
                for (int c = 0; c < 8; ++c)
                    a = fmaf(q[c], K[c * SQC + h * SH + w * SW + z], a);
                e[zi] = (z == d) ? -INFINITY : a;
            }
            float cm = e[0];
#pragma unroll
            for (int zi = 1; zi < 8; ++zi) cm = fmaxf(cm, e[zi]);
            const float nm = fmaxf(m, cm);
            float s = 0.f;
#pragma unroll
            for (int zi = 0; zi < 8; ++zi) s += __expf(e[zi] - nm);
            l = fmaf(l, __expf(m - nm), s);
            m = nm;
        }
    }

    __shared__ float sm[3][64], sl[3][64];
    sm[axis][d] = m;
    sl[axis][d] = l;
    __syncthreads();

    if (tid < 64) {
        const float m0 = sm[0][d], m1 = sm[1][d], m2 = sm[2][d];
        const float M  = fmaxf(fmaxf(m0, m1), m2);
        const float L  = sl[0][d] * __expf(m0 - M)
                       + sl[1][d] * __expf(m1 - M)
                       + sl[2][d] * __expf(m2 - M);
        const int idx = h * SH + w * SW + d;
        m_ws[idx]  = M;
        rl_ws[idx] = 1.0f / L;
    }
}

// ---------------------------------------------------------------------------
// K2: D-axis pass. Block = (h,w), one wave. out[c][d] = sum_z V[c,h,w,z]*A[z][d].
// Writes out (first pass; d_out is poisoned before every launch).
// ---------------------------------------------------------------------------
__global__ __launch_bounds__(64) void k_dpass(
    const float* __restrict__ Q, const float* __restrict__ K, const float* __restrict__ V,
    const float* __restrict__ m_ws, const float* __restrict__ rl_ws,
    float* __restrict__ out)
{
    __shared__ float VDT[64][68];   // [z][c], +4 pad for staging writes
    __shared__ float AZ[64][64];    // [z][d]
    __shared__ float KD[8][64];     // [c][z]

    const int lane = threadIdx.x;                 // = d for energy role
    const int h = blockIdx.x >> 6, w = blockIdx.x & 63;
    const int base = h * SH + w * SW;

#pragma unroll
    for (int c = 0; c < 8; ++c) KD[c][lane] = K[c * SQC + base + lane];

    // stage V transposed: VDT[z=lane][c]
#pragma unroll
    for (int cq = 0; cq < 16; ++cq) {
        float4 v;
        v.x = V[(4 * cq + 0) * SQC + base + lane];
        v.y = V[(4 * cq + 1) * SQC + base + lane];
        v.z = V[(4 * cq + 2) * SQC + base + lane];
        v.w = V[(4 * cq + 3) * SQC + base + lane];
        *reinterpret_cast<float4*>(&VDT[lane][4 * cq]) = v;
    }

    float q[8];
#pragma unroll
    for (int c = 0; c < 8; ++c) q[c] = Q[c * SQC + base + lane];

    __syncthreads();

    // energies for query d=lane vs all z
    float e[64];
#pragma unroll
    for (int z = 0; z < 64; ++z) e[z] = 0.f;
#pragma unroll
    for (int c = 0; c < 8; ++c) {
#pragma unroll
        for (int zq = 0; zq < 16; ++zq) {
            const float4 k4 = *reinterpret_cast<const float4*>(&KD[c][4 * zq]);
            e[4 * zq + 0] = fmaf(q[c], k4.x, e[4 * zq + 0]);
            e[4 * zq + 1] = fmaf(q[c], k4.y, e[4 * zq + 1]);
            e[4 * zq + 2] = fmaf(q[c], k4.z, e[4 * zq + 2]);
            e[4 * zq + 3] = fmaf(q[c], k4.w, e[4 * zq + 3]);
        }
    }
    const int qidx = base + lane;
    const float m  = m_ws[qidx];
    const float rl = rl_ws[qidx];
#pragma unroll
    for (int z = 0; z < 64; ++z)
        AZ[z][lane] = (z == lane) ? 0.f : __expf(e[z] - m) * rl;

    __syncthreads();

    // 64x64x64 matmul, 8x8 per lane
    const int i = lane >> 3, j = lane & 7;
    float acc[8][8];
#pragma unroll
    for (int a = 0; a < 8; ++a)
#pragma unroll
        for (int b = 0; b < 8; ++b) acc[a][b] = 0.f;

#pragma unroll 4
    for (int z = 0; z < 64; ++z) {
        float va[8], vb[8];
        *reinterpret_cast<float4*>(&va[0]) = *reinterpret_cast<const float4*>(&VDT[z][8 * i]);
        *reinterpret_cast<float4*>(&va[4]) = *reinterpret_cast<const float4*>(&VDT[z][8 * i + 4]);
        *reinterpret_cast<float4*>(&vb[0]) = *reinterpret_cast<const float4*>(&AZ[z][8 * j]);
        *reinterpret_cast<float4*>(&vb[4]) = *reinterpret_cast<const float4*>(&AZ[z][8 * j + 4]);
#pragma unroll
        for (int a = 0; a < 8; ++a)
#pragma unroll
            for (int b = 0; b < 8; ++b)
                acc[a][b] = fmaf(va[a], vb[b], acc[a][b]);
    }

#pragma unroll
    for (int a = 0; a < 8; ++a) {
        const float4 o0 = make_float4(acc[a][0], acc[a][1], acc[a][2], acc[a][3]);
        const float4 o1 = make_float4(acc[a][4], acc[a][5], acc[a][6], acc[a][7]);
        float* op = &out[(8 * i + a) * SQC + base + 8 * j];
        *reinterpret_cast<float4*>(op)     = o0;
        *reinterpret_cast<float4*>(op + 4) = o1;
    }
}

// ---------------------------------------------------------------------------
// K3: H-axis pass. Block = (w, 16-h tile), 1024 thr. Streams x; V read once.
// out[c, hbase+ha, w, d] += sum_x V[c,x,w,d] * A_H[ha][d](x).
// ---------------------------------------------------------------------------
__global__ __launch_bounds__(1024, 4) void k_hpass(
    const float* __restrict__ Q, const float* __restrict__ K, const float* __restrict__ V,
    const float* __restrict__ m_ws, const float* __restrict__ rl_ws,
    float* __restrict__ out)
{
    __shared__ float Kx[8][64];
    __shared__ float Vx[64][64];
    __shared__ float Ax[16][64];

    const int tid = threadIdx.x;
    const int d   = tid & 63;
    const int g   = tid >> 6;                  // 0..15
    const int w     = blockIdx.x & 63;
    const int hbase = (blockIdx.x >> 6) << 4;  // 0,16,32,48

    // energy role: query (h_e, w, d)
    const int h_e = hbase + g;
    float q[8];
#pragma unroll
    for (int c = 0; c < 8; ++c) q[c] = Q[c * SQC + h_e * SH + w * SW + d];
    const int qidx = h_e * SH + w * SW + d;
    const float m = m_ws[qidx], rl = rl_ws[qidx];

    // MAC role: c-octet co, h-octet hh
    const int co = g & 7, hh = g >> 3;
    float acc[8][8];
#pragma unroll
    for (int a = 0; a < 8; ++a)
#pragma unroll
        for (int b = 0; b < 8; ++b) acc[a][b] = 0.f;

    for (int x = 0; x < 64; ++x) {
        if (tid < 512) Kx[tid >> 6][d] = K[(tid >> 6) * SQC + x * SH + w * SW + d];
#pragma unroll
        for (int r = 0; r < 4; ++r) {
            const int c = r * 16 + g;
            Vx[c][d] = V[c * SQC + x * SH + w * SW + d];
        }
        __syncthreads();

        float e = 0.f;
#pragma unroll
        for (int c = 0; c < 8; ++c) e = fmaf(q[c], Kx[c][d], e);
        Ax[g][d] = (x == h_e) ? 0.f : __expf(e - m) * rl;
        __syncthreads();

        float va[8], pa[8];
#pragma unroll
        for (int cc = 0; cc < 8; ++cc) va[cc] = Vx[8 * co + cc][d];
#pragma unroll
        for (int aa = 0; aa < 8; ++aa) pa[aa] = Ax[8 * hh + aa][d];
#pragma unroll
        for (int cc = 0; cc < 8; ++cc)
#pragma unroll
            for (int aa = 0; aa < 8; ++aa)
                acc[cc][aa] = fmaf(va[cc], pa[aa], acc[cc][aa]);
        __syncthreads();
    }

#pragma unroll
    for (int cc = 0; cc < 8; ++cc)
#pragma unroll
        for (int aa = 0; aa < 8; ++aa) {
            float* op = &out[(8 * co + cc) * SQC + (hbase + 8 * hh + aa) * SH + w * SW + d];
            *op += acc[cc][aa];
        }
}

// ---------------------------------------------------------------------------
// K4: W-axis pass. Block = (h, 16-w tile), 1024 thr. Streams y; no mask.
// out[c, h, wbase+wa, d] += sum_y V[c,h,y,d] * A_W[wa][d](y).
// ---------------------------------------------------------------------------
__global__ __launch_bounds__(1024, 4) void k_wpass(
    const float* __restrict__ Q, const float* __restrict__ K, const float* __restrict__ V,
    const float* __restrict__ m_ws, const float* __restrict__ rl_ws,
    float* __restrict__ out)
{
    __shared__ float Ky[8][64];
    __shared__ float Vy[64][64];
    __shared__ float Ay[16][64];

    const int tid = threadIdx.x;
    const int d   = tid & 63;
    const int g   = tid >> 6;
    const int h     = blockIdx.x & 63;
    const int wbase = (blockIdx.x >> 6) << 4;

    const int w_e = wbase + g;
    float q[8];
#pragma unroll
    for (int c = 0; c < 8; ++c) q[c] = Q[c * SQC + h * SH + w_e * SW + d];
    const int qidx = h * SH + w_e * SW + d;
    const float m = m_ws[qidx], rl = rl_ws[qidx];

    const int co = g & 7, wh = g >> 3;
    float acc[8][8];
#pragma unroll
    for (int a = 0; a < 8; ++a)
#pragma unroll
        for (int b = 0; b < 8; ++b) acc[a][b] = 0.f;

    for (int y = 0; y < 64; ++y) {
        if (tid < 512) Ky[tid >> 6][d] = K[(tid >> 6) * SQC + h * SH + y * SW + d];
#pragma unroll
        for (int r = 0; r < 4; ++r) {
            const int c = r * 16 + g;
            Vy[c][d] = V[c * SQC + h * SH + y * SW + d];
        }
        __syncthreads();

        float e = 0.f;
#pragma unroll
        for (int c = 0; c < 8; ++c) e = fmaf(q[c], Ky[c][d], e);
        Ay[g][d] = __expf(e - m) * rl;      // no diagonal mask on W
        __syncthreads();

        float va[8], pa[8];
#pragma unroll
        for (int cc = 0; cc < 8; ++cc) va[cc] = Vy[8 * co + cc][d];
#pragma unroll
        for (int ww = 0; ww < 8; ++ww) pa[ww] = Ay[8 * wh + ww][d];
#pragma unroll
        for (int cc = 0; cc < 8; ++cc)
#pragma unroll
            for (int ww = 0; ww < 8; ++ww)
                acc[cc][ww] = fmaf(va[cc], pa[ww], acc[cc][ww]);
        __syncthreads();
    }

#pragma unroll
    for (int cc = 0; cc < 8; ++cc)
#pragma unroll
        for (int ww = 0; ww < 8; ++ww) {
            float* op = &out[(8 * co + cc) * SQC + h * SH + (wbase + 8 * wh + ww) * SW + d];
            *op += acc[cc][ww];
        }
}

// ---------------------------------------------------------------------------
extern "C" void kernel_launch(void* const* d_in, const int* in_sizes, int n_in,
                              void* d_out, int out_size, void* d_ws, size_t ws_size,
                              hipStream_t stream)
{
    const float* Q = (const float*)d_in[0];
    const float* K = (const float*)d_in[1];
    const float* V = (const float*)d_in[2];
    float* out = (float*)d_out;

    float* m_ws  = (float*)d_ws;          // 262144 floats
    float* rl_ws = m_ws + SQC;            // 262144 floats (ws needs 2 MB)

    hipLaunchKernelGGL(k_stats, dim3(4096), dim3(192),  0, stream, Q, K, m_ws, rl_ws);
    hipLaunchKernelGGL(k_dpass, dim3(4096), dim3(64),   0, stream, Q, K, V, m_ws, rl_ws, out);
    hipLaunchKernelGGL(k_hpass, dim3(256),  dim3(1024), 0, stream, Q, K, V, m_ws, rl_ws, out);
    hipLaunchKernelGGL(k_wpass, dim3(256),  dim3(1024), 0, stream, Q, K, V, m_ws, rl_ws, out);
}

// Round 5
// 444.868 us; speedup vs baseline: 1.4036x; 1.4036x over previous
//
#include <hip/hip_runtime.h>
#include <math.h>

// Problem constants: B=1, CQ=8, CV=64, H=W=D=64, fp32.
#define SQC 262144   // channel stride = 64*64*64
#define SH  4096     // h stride = 64*64
#define SW  64       // w stride

// ---------------------------------------------------------------------------
// K1a/K1b: per-axis softmax partial stats via LDS-staged streaming K.
// AXIS=0 (H): block = (w fixed, 16-h tile); stream x; mask x == h_query.
// AXIS=1 (W): block = (h fixed, 16-w tile); stream y; no mask.
// 1024 thr: d = tid&63, g = tid>>6 -> query (mbase+g). 8 chunks of 8 keys:
// stage K[8 keys][8 c][64 d] (16 KB) once per chunk; every thread then does
// 64 LDS reads + 64 FMA. Global K loads: 1 per row per block (coalesced),
// vs 1 per row per THREAD in the old k_stats (the 22-cyc/load L1-miss wall).
// ---------------------------------------------------------------------------
template <int AXIS>
__global__ __launch_bounds__(1024) void k_stats_hw(
    const float* __restrict__ Q, const float* __restrict__ K,
    float* __restrict__ m_out, float* __restrict__ l_out)
{
    __shared__ float Kc[8][8][64];   // [key-in-chunk][c][d]

    const int tid   = threadIdx.x;
    const int d     = tid & 63;
    const int g     = tid >> 6;                 // 0..15
    const int fixed = blockIdx.x & 63;          // w (AXIS=0) or h (AXIS=1)
    const int mbase = (blockIdx.x >> 6) << 4;   // query-tile base on moving axis

    const int MS = (AXIS == 0) ? SH : SW;       // stride of streamed key index
    const int FS = (AXIS == 0) ? SW : SH;       // stride of fixed index

    // query: AXIS=0 -> (h=mbase+g, w=fixed); AXIS=1 -> (h=fixed, w=mbase+g)
    const int qoff = (AXIS == 0) ? ((mbase + g) * SH + fixed * SW + d)
                                 : (fixed * SH + (mbase + g) * SW + d);
    float q[8];
#pragma unroll
    for (int c = 0; c < 8; ++c) q[c] = Q[c * SQC + qoff];

    float m = -INFINITY, l = 0.f;

#pragma unroll 1
    for (int kc = 0; kc < 8; ++kc) {
        // stage 8 key-rows x 8 channels x 64 d
#pragma unroll
        for (int j = 0; j < 4; ++j) {
            const int t  = tid + j * 1024;
            const int xi = t >> 9;
            const int c  = (t >> 6) & 7;
            const int dd = t & 63;
            Kc[xi][c][dd] = K[c * SQC + (kc * 8 + xi) * MS + fixed * FS + dd];
        }
        __syncthreads();

        float e[8];
#pragma unroll
        for (int xi = 0; xi < 8; ++xi) {
            float a = 0.f;
#pragma unroll
            for (int c = 0; c < 8; ++c)
                a = fmaf(q[c], Kc[xi][c][d], a);
            if (AXIS == 0 && (kc * 8 + xi) == (mbase + g)) a = -INFINITY;
            e[xi] = a;
        }
        float cm = e[0];
#pragma unroll
        for (int xi = 1; xi < 8; ++xi) cm = fmaxf(cm, e[xi]);
        const float nm = fmaxf(m, cm);
        float s = 0.f;
#pragma unroll
        for (int xi = 0; xi < 8; ++xi) s += __expf(e[xi] - nm);
        l = fmaf(l, __expf(m - nm), s);
        m = nm;
        __syncthreads();
    }

    m_out[qoff] = m;
    l_out[qoff] = l;
}

// ---------------------------------------------------------------------------
// K1c: D-axis stats + 3-way merge. Block = one (h,w) line, 1 wave, lane = d.
// K line staged once in LDS (2 KB); energy reads are wave-uniform broadcasts
// (conflict-free). Runs AFTER k_stats_hw; reads their partials, writes final
// M and 1/L used by all PV passes.
// ---------------------------------------------------------------------------
__global__ __launch_bounds__(64) void k_stats_d(
    const float* __restrict__ Q, const float* __restrict__ K,
    const float* __restrict__ mH, const float* __restrict__ lH,
    const float* __restrict__ mW, const float* __restrict__ lW,
    float* __restrict__ M_out, float* __restrict__ RL_out)
{
    __shared__ float KD[8][64];

    const int lane = threadIdx.x;   // = d
    const int h = blockIdx.x >> 6, w = blockIdx.x & 63;
    const int base = h * SH + w * SW;

#pragma unroll
    for (int c = 0; c < 8; ++c) KD[c][lane] = K[c * SQC + base + lane];

    float q[8];
#pragma unroll
    for (int c = 0; c < 8; ++c) q[c] = Q[c * SQC + base + lane];
    __syncthreads();

    float m = -INFINITY, l = 0.f;
#pragma unroll 1
    for (int zc = 0; zc < 8; ++zc) {
        float e[8];
#pragma unroll
        for (int zi = 0; zi < 8; ++zi) {
            const int z = zc * 8 + zi;
            float a = 0.f;
#pragma unroll
            for (int c = 0; c < 8; ++c)
                a = fmaf(q[c], KD[c][z], a);
            e[zi] = (z == lane) ? -INFINITY : a;
        }
        float cm = e[0];
#pragma unroll
        for (int zi = 1; zi < 8; ++zi) cm = fmaxf(cm, e[zi]);
        const float nm = fmaxf(m, cm);
        float s = 0.f;
#pragma unroll
        for (int zi = 0; zi < 8; ++zi) s += __expf(e[zi] - nm);
        l = fmaf(l, __expf(m - nm), s);
        m = nm;
    }

    // merge with H and W partials
    const int idx = base + lane;
    const float m0 = mH[idx], l0 = lH[idx];
    const float m1 = mW[idx], l1 = lW[idx];
    const float M  = fmaxf(fmaxf(m0, m1), m);
    const float L  = l0 * __expf(m0 - M) + l1 * __expf(m1 - M) + l * __expf(m - M);
    M_out[idx]  = M;
    RL_out[idx] = 1.0f / L;
}

// ---------------------------------------------------------------------------
// K2: D-axis pass. Block = (h,w), one wave. out[c][d] = sum_z V[c,h,w,z]*A[z][d].
// Writes out (first pass; d_out is poisoned before every launch).
// ---------------------------------------------------------------------------
__global__ __launch_bounds__(64) void k_dpass(
    const float* __restrict__ Q, const float* __restrict__ K, const float* __restrict__ V,
    const float* __restrict__ m_ws, const float* __restrict__ rl_ws,
    float* __restrict__ out)
{
    __shared__ float VDT[64][68];   // [z][c], +4 pad for staging writes
    __shared__ float AZ[64][64];    // [z][d]
    __shared__ float KD[8][64];     // [c][z]

    const int lane = threadIdx.x;                 // = d for energy role
    const int h = blockIdx.x >> 6, w = blockIdx.x & 63;
    const int base = h * SH + w * SW;

#pragma unroll
    for (int c = 0; c < 8; ++c) KD[c][lane] = K[c * SQC + base + lane];

    // stage V transposed: VDT[z=lane][c]
#pragma unroll
    for (int cq = 0; cq < 16; ++cq) {
        float4 v;
        v.x = V[(4 * cq + 0) * SQC + base + lane];
        v.y = V[(4 * cq + 1) * SQC + base + lane];
        v.z = V[(4 * cq + 2) * SQC + base + lane];
        v.w = V[(4 * cq + 3) * SQC + base + lane];
        *reinterpret_cast<float4*>(&VDT[lane][4 * cq]) = v;
    }

    float q[8];
#pragma unroll
    for (int c = 0; c < 8; ++c) q[c] = Q[c * SQC + base + lane];

    __syncthreads();

    // energies for query d=lane vs all z
    float e[64];
#pragma unroll
    for (int z = 0; z < 64; ++z) e[z] = 0.f;
#pragma unroll
    for (int c = 0; c < 8; ++c) {
#pragma unroll
        for (int zq = 0; zq < 16; ++zq) {
            const float4 k4 = *reinterpret_cast<const float4*>(&KD[c][4 * zq]);
            e[4 * zq + 0] = fmaf(q[c], k4.x, e[4 * zq + 0]);
            e[4 * zq + 1] = fmaf(q[c], k4.y, e[4 * zq + 1]);
            e[4 * zq + 2] = fmaf(q[c], k4.z, e[4 * zq + 2]);
            e[4 * zq + 3] = fmaf(q[c], k4.w, e[4 * zq + 3]);
        }
    }
    const int qidx = base + lane;
    const float m  = m_ws[qidx];
    const float rl = rl_ws[qidx];
#pragma unroll
    for (int z = 0; z < 64; ++z)
        AZ[z][lane] = (z == lane) ? 0.f : __expf(e[z] - m) * rl;

    __syncthreads();

    // 64x64x64 matmul, 8x8 per lane
    const int i = lane >> 3, j = lane & 7;
    float acc[8][8];
#pragma unroll
    for (int a = 0; a < 8; ++a)
#pragma unroll
        for (int b = 0; b < 8; ++b) acc[a][b] = 0.f;

#pragma unroll 4
    for (int z = 0; z < 64; ++z) {
        float va[8], vb[8];
        *reinterpret_cast<float4*>(&va[0]) = *reinterpret_cast<const float4*>(&VDT[z][8 * i]);
        *reinterpret_cast<float4*>(&va[4]) = *reinterpret_cast<const float4*>(&VDT[z][8 * i + 4]);
        *reinterpret_cast<float4*>(&vb[0]) = *reinterpret_cast<const float4*>(&AZ[z][8 * j]);
        *reinterpret_cast<float4*>(&vb[4]) = *reinterpret_cast<const float4*>(&AZ[z][8 * j + 4]);
#pragma unroll
        for (int a = 0; a < 8; ++a)
#pragma unroll
            for (int b = 0; b < 8; ++b)
                acc[a][b] = fmaf(va[a], vb[b], acc[a][b]);
    }

#pragma unroll
    for (int a = 0; a < 8; ++a) {
        const float4 o0 = make_float4(acc[a][0], acc[a][1], acc[a][2], acc[a][3]);
        const float4 o1 = make_float4(acc[a][4], acc[a][5], acc[a][6], acc[a][7]);
        float* op = &out[(8 * i + a) * SQC + base + 8 * j];
        *reinterpret_cast<float4*>(op)     = o0;
        *reinterpret_cast<float4*>(op + 4) = o1;
    }
}

// ---------------------------------------------------------------------------
// K3: H-axis pass. Block = (w, 16-h tile), 1024 thr. Streams x; V read once.
// out[c, hbase+ha, w, d] += sum_x V[c,x,w,d] * A_H[ha][d](x).
// ---------------------------------------------------------------------------
__global__ __launch_bounds__(1024, 4) void k_hpass(
    const float* __restrict__ Q, const float* __restrict__ K, const float* __restrict__ V,
    const float* __restrict__ m_ws, const float* __restrict__ rl_ws,
    float* __restrict__ out)
{
    __shared__ float Kx[8][64];
    __shared__ float Vx[64][64];
    __shared__ float Ax[16][64];

    const int tid = threadIdx.x;
    const int d   = tid & 63;
    const int g   = tid >> 6;                  // 0..15
    const int w     = blockIdx.x & 63;
    const int hbase = (blockIdx.x >> 6) << 4;  // 0,16,32,48

    // energy role: query (h_e, w, d)
    const int h_e = hbase + g;
    float q[8];
#pragma unroll
    for (int c = 0; c < 8; ++c) q[c] = Q[c * SQC + h_e * SH + w * SW + d];
    const int qidx = h_e * SH + w * SW + d;
    const float m = m_ws[qidx], rl = rl_ws[qidx];

    // MAC role: c-octet co, h-octet hh
    const int co = g & 7, hh = g >> 3;
    float acc[8][8];
#pragma unroll
    for (int a = 0; a < 8; ++a)
#pragma unroll
        for (int b = 0; b < 8; ++b) acc[a][b] = 0.f;

    for (int x = 0; x < 64; ++x) {
        if (tid < 512) Kx[tid >> 6][d] = K[(tid >> 6) * SQC + x * SH + w * SW + d];
#pragma unroll
        for (int r = 0; r < 4; ++r) {
            const int c = r * 16 + g;
            Vx[c][d] = V[c * SQC + x * SH + w * SW + d];
        }
        __syncthreads();

        float e = 0.f;
#pragma unroll
        for (int c = 0; c < 8; ++c) e = fmaf(q[c], Kx[c][d], e);
        Ax[g][d] = (x == h_e) ? 0.f : __expf(e - m) * rl;
        __syncthreads();

        float va[8], pa[8];
#pragma unroll
        for (int cc = 0; cc < 8; ++cc) va[cc] = Vx[8 * co + cc][d];
#pragma unroll
        for (int aa = 0; aa < 8; ++aa) pa[aa] = Ax[8 * hh + aa][d];
#pragma unroll
        for (int cc = 0; cc < 8; ++cc)
#pragma unroll
            for (int aa = 0; aa < 8; ++aa)
                acc[cc][aa] = fmaf(va[cc], pa[aa], acc[cc][aa]);
        __syncthreads();
    }

#pragma unroll
    for (int cc = 0; cc < 8; ++cc)
#pragma unroll
        for (int aa = 0; aa < 8; ++aa) {
            float* op = &out[(8 * co + cc) * SQC + (hbase + 8 * hh + aa) * SH + w * SW + d];
            *op += acc[cc][aa];
        }
}

// ---------------------------------------------------------------------------
// K4: W-axis pass. Block = (h, 16-w tile), 1024 thr. Streams y; no mask.
// out[c, h, wbase+wa, d] += sum_y V[c,h,y,d] * A_W[wa][d](y).
// ---------------------------------------------------------------------------
__global__ __launch_bounds__(1024, 4) void k_wpass(
    const float* __restrict__ Q, const float* __restrict__ K, const float* __restrict__ V,
    const float* __restrict__ m_ws, const float* __restrict__ rl_ws,
    float* __restrict__ out)
{
    __shared__ float Ky[8][64];
    __shared__ float Vy[64][64];
    __shared__ float Ay[16][64];

    const int tid = threadIdx.x;
    const int d   = tid & 63;
    const int g   = tid >> 6;
    const int h     = blockIdx.x & 63;
    const int wbase = (blockIdx.x >> 6) << 4;

    const int w_e = wbase + g;
    float q[8];
#pragma unroll
    for (int c = 0; c < 8; ++c) q[c] = Q[c * SQC + h * SH + w_e * SW + d];
    const int qidx = h * SH + w_e * SW + d;
    const float m = m_ws[qidx], rl = rl_ws[qidx];

    const int co = g & 7, wh = g >> 3;
    float acc[8][8];
#pragma unroll
    for (int a = 0; a < 8; ++a)
#pragma unroll
        for (int b = 0; b < 8; ++b) acc[a][b] = 0.f;

    for (int y = 0; y < 64; ++y) {
        if (tid < 512) Ky[tid >> 6][d] = K[(tid >> 6) * SQC + h * SH + y * SW + d];
#pragma unroll
        for (int r = 0; r < 4; ++r) {
            const int c = r * 16 + g;
            Vy[c][d] = V[c * SQC + h * SH + y * SW + d];
        }
        __syncthreads();

        float e = 0.f;
#pragma unroll
        for (int c = 0; c < 8; ++c) e = fmaf(q[c], Ky[c][d], e);
        Ay[g][d] = __expf(e - m) * rl;      // no diagonal mask on W
        __syncthreads();

        float va[8], pa[8];
#pragma unroll
        for (int cc = 0; cc < 8; ++cc) va[cc] = Vy[8 * co + cc][d];
#pragma unroll
        for (int ww = 0; ww < 8; ++ww) pa[ww] = Ay[8 * wh + ww][d];
#pragma unroll
        for (int cc = 0; cc < 8; ++cc)
#pragma unroll
            for (int ww = 0; ww < 8; ++ww)
                acc[cc][ww] = fmaf(va[cc], pa[ww], acc[cc][ww]);
        __syncthreads();
    }

#pragma unroll
    for (int cc = 0; cc < 8; ++cc)
#pragma unroll
        for (int ww = 0; ww < 8; ++ww) {
            float* op = &out[(8 * co + cc) * SQC + h * SH + (wbase + 8 * wh + ww) * SW + d];
            *op += acc[cc][ww];
        }
}

// ---------------------------------------------------------------------------
extern "C" void kernel_launch(void* const* d_in, const int* in_sizes, int n_in,
                              void* d_out, int out_size, void* d_ws, size_t ws_size,
                              hipStream_t stream)
{
    const float* Q = (const float*)d_in[0];
    const float* K = (const float*)d_in[1];
    const float* V = (const float*)d_in[2];
    float* out = (float*)d_out;

    // ws layout (floats): mH, lH, mW, lW, M, RL  -> 6 MB total
    float* mH = (float*)d_ws;
    float* lH = mH + SQC;
    float* mW = lH + SQC;
    float* lW = mW + SQC;
    float* M  = lW + SQC;
    float* RL = M  + SQC;

    hipLaunchKernelGGL((k_stats_hw<0>), dim3(256), dim3(1024), 0, stream, Q, K, mH, lH);
    hipLaunchKernelGGL((k_stats_hw<1>), dim3(256), dim3(1024), 0, stream, Q, K, mW, lW);
    hipLaunchKernelGGL(k_stats_d, dim3(4096), dim3(64), 0, stream, Q, K, mH, lH, mW, lW, M, RL);
    hipLaunchKernelGGL(k_dpass, dim3(4096), dim3(64),   0, stream, Q, K, V, M, RL, out);
    hipLaunchKernelGGL(k_hpass, dim3(256),  dim3(1024), 0, stream, Q, K, V, M, RL, out);
    hipLaunchKernelGGL(k_wpass, dim3(256),  dim3(1024), 0, stream, Q, K, V, M, RL, out);
}

// Round 8
// 352.182 us; speedup vs baseline: 1.7730x; 1.2632x over previous
//
#include <hip/hip_runtime.h>
#include <math.h>

// Problem constants: B=1, CQ=8, CV=64, H=W=D=64, fp32.
#define SQC 262144   // channel stride = 64*64*64
#define SH  4096     // h stride = 64*64
#define SW  64       // w stride

// ---------------------------------------------------------------------------
// K1a/K1b: per-axis softmax partial stats via LDS-staged streaming K.
// (unchanged from round 5)
// ---------------------------------------------------------------------------
template <int AXIS>
__global__ __launch_bounds__(1024) void k_stats_hw(
    const float* __restrict__ Q, const float* __restrict__ K,
    float* __restrict__ m_out, float* __restrict__ l_out)
{
    __shared__ float Kc[8][8][64];   // [key-in-chunk][c][d]

    const int tid   = threadIdx.x;
    const int d     = tid & 63;
    const int g     = tid >> 6;                 // 0..15
    const int fixed = blockIdx.x & 63;          // w (AXIS=0) or h (AXIS=1)
    const int mbase = (blockIdx.x >> 6) << 4;   // query-tile base on moving axis

    const int MS = (AXIS == 0) ? SH : SW;       // stride of streamed key index
    const int FS = (AXIS == 0) ? SW : SH;       // stride of fixed index

    const int qoff = (AXIS == 0) ? ((mbase + g) * SH + fixed * SW + d)
                                 : (fixed * SH + (mbase + g) * SW + d);
    float q[8];
#pragma unroll
    for (int c = 0; c < 8; ++c) q[c] = Q[c * SQC + qoff];

    float m = -INFINITY, l = 0.f;

#pragma unroll 1
    for (int kc = 0; kc < 8; ++kc) {
#pragma unroll
        for (int j = 0; j < 4; ++j) {
            const int t  = tid + j * 1024;
            const int xi = t >> 9;
            const int c  = (t >> 6) & 7;
            const int dd = t & 63;
            Kc[xi][c][dd] = K[c * SQC + (kc * 8 + xi) * MS + fixed * FS + dd];
        }
        __syncthreads();

        float e[8];
#pragma unroll
        for (int xi = 0; xi < 8; ++xi) {
            float a = 0.f;
#pragma unroll
            for (int c = 0; c < 8; ++c)
                a = fmaf(q[c], Kc[xi][c][d], a);
            if (AXIS == 0 && (kc * 8 + xi) == (mbase + g)) a = -INFINITY;
            e[xi] = a;
        }
        float cm = e[0];
#pragma unroll
        for (int xi = 1; xi < 8; ++xi) cm = fmaxf(cm, e[xi]);
        const float nm = fmaxf(m, cm);
        float s = 0.f;
#pragma unroll
        for (int xi = 0; xi < 8; ++xi) s += __expf(e[xi] - nm);
        l = fmaf(l, __expf(m - nm), s);
        m = nm;
        __syncthreads();
    }

    m_out[qoff] = m;
    l_out[qoff] = l;
}

// ---------------------------------------------------------------------------
// K2: fused D-axis stats + merge + D-axis PV pass.
// Block = one (h,w) line, 256 threads (4 waves).
// BUGFIX vs round 6: V staging now covers ALL 64 channels (16 per thread,
// c0 = 16*zq + 4*j), not just 0..15.
// ---------------------------------------------------------------------------
__global__ __launch_bounds__(256) void k_dpass(
    const float* __restrict__ Q, const float* __restrict__ K, const float* __restrict__ V,
    const float* __restrict__ mH, const float* __restrict__ lH,
    const float* __restrict__ mW, const float* __restrict__ lW,
    float* __restrict__ M_out, float* __restrict__ RL_out,
    float* __restrict__ out)
{
    __shared__ float KD[8][64];     // [c][z]
    __shared__ float VDT[64][68];   // [z][c], +4 pad
    __shared__ float AZ[64][64];    // [z][d]
    __shared__ float sm[4][64], sl[4][64], Ms[64], RLs[64];

    const int tid = threadIdx.x;
    const int d   = tid & 63;
    const int zq  = tid >> 6;                 // 0..3
    const int h = blockIdx.x >> 6, w = blockIdx.x & 63;
    const int base = h * SH + w * SW;

    // stage K line: 512 floats via 128 float4
    if (tid < 128) {
        const int c = tid >> 4, dv = (tid & 15) * 4;
        *reinterpret_cast<float4*>(&KD[c][dv]) =
            *reinterpret_cast<const float4*>(&K[c * SQC + base + dv]);
    }
    // stage V transposed: thread (z = d, zq) loads channels 16*zq .. 16*zq+15
#pragma unroll
    for (int j = 0; j < 4; ++j) {
        const int c0 = 16 * zq + 4 * j;
        float4 v;
        v.x = V[(c0 + 0) * SQC + base + d];
        v.y = V[(c0 + 1) * SQC + base + d];
        v.z = V[(c0 + 2) * SQC + base + d];
        v.w = V[(c0 + 3) * SQC + base + d];
        *reinterpret_cast<float4*>(&VDT[d][c0]) = v;
    }

    float q[8];
#pragma unroll
    for (int c = 0; c < 8; ++c) q[c] = Q[c * SQC + base + d];
    __syncthreads();

    // energies for query d over z = zq*16 .. zq*16+15 (KD reads are broadcasts)
    float e[16];
#pragma unroll
    for (int zi = 0; zi < 16; ++zi) {
        const int z = zq * 16 + zi;
        float a = 0.f;
#pragma unroll
        for (int c = 0; c < 8; ++c)
            a = fmaf(q[c], KD[c][z], a);
        e[zi] = (z == d) ? -INFINITY : a;
    }
    float pm = e[0];
#pragma unroll
    for (int zi = 1; zi < 16; ++zi) pm = fmaxf(pm, e[zi]);
    float pl = 0.f;
#pragma unroll
    for (int zi = 0; zi < 16; ++zi) pl += __expf(e[zi] - pm);
    sm[zq][d] = pm;
    sl[zq][d] = pl;
    __syncthreads();

    // merge 4 z-partials + H/W partials -> final M, RL
    if (tid < 64) {
        const float m0 = sm[0][d], m1 = sm[1][d], m2 = sm[2][d], m3 = sm[3][d];
        const float mD = fmaxf(fmaxf(m0, m1), fmaxf(m2, m3));
        const float lD = sl[0][d] * __expf(m0 - mD) + sl[1][d] * __expf(m1 - mD)
                       + sl[2][d] * __expf(m2 - mD) + sl[3][d] * __expf(m3 - mD);
        const int idx = base + d;
        const float mh = mH[idx], mw = mW[idx];
        const float M  = fmaxf(fmaxf(mh, mw), mD);
        const float L  = lH[idx] * __expf(mh - M) + lW[idx] * __expf(mw - M)
                       + lD * __expf(mD - M);
        const float RL = 1.0f / L;
        M_out[idx]  = M;
        RL_out[idx] = RL;
        Ms[d]  = M;
        RLs[d] = RL;
    }
    __syncthreads();

    // attention matrix from register energies
    {
        const float M = Ms[d], RL = RLs[d];
#pragma unroll
        for (int zi = 0; zi < 16; ++zi) {
            const int z = zq * 16 + zi;
            AZ[z][d] = (z == d) ? 0.f : __expf(e[zi] - M) * RL;
        }
    }
    __syncthreads();

    // 64x64x64 matmul: out[4ci+a][4dj+b] = sum_z VDT[z][4ci+a] * AZ[z][4dj+b]
    const int ci = tid >> 4, dj = tid & 15;
    float acc[4][4];
#pragma unroll
    for (int a = 0; a < 4; ++a)
#pragma unroll
        for (int b = 0; b < 4; ++b) acc[a][b] = 0.f;

#pragma unroll 8
    for (int z = 0; z < 64; ++z) {
        const float4 va = *reinterpret_cast<const float4*>(&VDT[z][4 * ci]);
        const float4 vb = *reinterpret_cast<const float4*>(&AZ[z][4 * dj]);
        const float av[4] = {va.x, va.y, va.z, va.w};
        const float bv[4] = {vb.x, vb.y, vb.z, vb.w};
#pragma unroll
        for (int a = 0; a < 4; ++a)
#pragma unroll
            for (int b = 0; b < 4; ++b)
                acc[a][b] = fmaf(av[a], bv[b], acc[a][b]);
    }

#pragma unroll
    for (int a = 0; a < 4; ++a) {
        const float4 o = make_float4(acc[a][0], acc[a][1], acc[a][2], acc[a][3]);
        *reinterpret_cast<float4*>(&out[(4 * ci + a) * SQC + base + 4 * dj]) = o;
    }
}

// ---------------------------------------------------------------------------
// K3: H-axis pass, 4-x super-steps. Block = (w, 16-h tile), 1024 thr.
// ---------------------------------------------------------------------------
__global__ __launch_bounds__(1024) void k_hpass(
    const float* __restrict__ Q, const float* __restrict__ K, const float* __restrict__ V,
    const float* __restrict__ m_ws, const float* __restrict__ rl_ws,
    float* __restrict__ out)
{
    __shared__ float Kx[4][8][64];
    __shared__ float Vx[4][64][64];
    __shared__ float Ax[4][16][64];

    const int tid = threadIdx.x;
    const int d   = tid & 63;
    const int g   = tid >> 6;                  // 0..15
    const int w     = blockIdx.x & 63;
    const int hbase = (blockIdx.x >> 6) << 4;  // 0,16,32,48

    const int h_e = hbase + g;
    float q[8];
#pragma unroll
    for (int c = 0; c < 8; ++c) q[c] = Q[c * SQC + h_e * SH + w * SW + d];
    const int qidx = h_e * SH + w * SW + d;
    const float m = m_ws[qidx], rl = rl_ws[qidx];

    const int co = g & 7, hh = g >> 3;
    float acc[8][8];
#pragma unroll
    for (int a = 0; a < 8; ++a)
#pragma unroll
        for (int b = 0; b < 8; ++b) acc[a][b] = 0.f;

#pragma unroll 1
    for (int xs = 0; xs < 16; ++xs) {
        const int x0 = xs * 4;
        // stage V: 4096 float4s, 4 per thread
#pragma unroll
        for (int j = 0; j < 4; ++j) {
            const int u  = j * 1024 + tid;
            const int xi = u >> 10;
            const int c  = (u >> 4) & 63;
            const int dv = (u & 15) * 4;
            *reinterpret_cast<float4*>(&Vx[xi][c][dv]) =
                *reinterpret_cast<const float4*>(&V[c * SQC + (x0 + xi) * SH + w * SW + dv]);
        }
        // stage K: 512 float4s
        if (tid < 512) {
            const int xi = tid >> 7;
            const int c  = (tid >> 4) & 7;
            const int dv = (tid & 15) * 4;
            *reinterpret_cast<float4*>(&Kx[xi][c][dv]) =
                *reinterpret_cast<const float4*>(&K[c * SQC + (x0 + xi) * SH + w * SW + dv]);
        }
        __syncthreads();

        // energies for 4 x
#pragma unroll
        for (int xi = 0; xi < 4; ++xi) {
            float e = 0.f;
#pragma unroll
            for (int c = 0; c < 8; ++c) e = fmaf(q[c], Kx[xi][c][d], e);
            Ax[xi][g][d] = ((x0 + xi) == h_e) ? 0.f : __expf(e - m) * rl;
        }
        __syncthreads();

        // MAC over 4 x
#pragma unroll
        for (int xi = 0; xi < 4; ++xi) {
            float va[8], pa[8];
#pragma unroll
            for (int cc = 0; cc < 8; ++cc) va[cc] = Vx[xi][8 * co + cc][d];
#pragma unroll
            for (int aa = 0; aa < 8; ++aa) pa[aa] = Ax[xi][8 * hh + aa][d];
#pragma unroll
            for (int cc = 0; cc < 8; ++cc)
#pragma unroll
                for (int aa = 0; aa < 8; ++aa)
                    acc[cc][aa] = fmaf(va[cc], pa[aa], acc[cc][aa]);
        }
        __syncthreads();
    }

#pragma unroll
    for (int cc = 0; cc < 8; ++cc)
#pragma unroll
        for (int aa = 0; aa < 8; ++aa) {
            float* op = &out[(8 * co + cc) * SQC + (hbase + 8 * hh + aa) * SH + w * SW + d];
            *op += acc[cc][aa];
        }
}

// ---------------------------------------------------------------------------
// K4: W-axis pass, 4-y super-steps. Block = (h, 16-w tile), 1024 thr. No mask.
// ---------------------------------------------------------------------------
__global__ __launch_bounds__(1024) void k_wpass(
    const float* __restrict__ Q, const float* __restrict__ K, const float* __restrict__ V,
    const float* __restrict__ m_ws, const float* __restrict__ rl_ws,
    float* __restrict__ out)
{
    __shared__ float Ky[4][8][64];
    __shared__ float Vy[4][64][64];
    __shared__ float Ay[4][16][64];

    const int tid = threadIdx.x;
    const int d   = tid & 63;
    const int g   = tid >> 6;
    const int h     = blockIdx.x & 63;
    const int wbase = (blockIdx.x >> 6) << 4;

    const int w_e = wbase + g;
    float q[8];
#pragma unroll
    for (int c = 0; c < 8; ++c) q[c] = Q[c * SQC + h * SH + w_e * SW + d];
    const int qidx = h * SH + w_e * SW + d;
    const float m = m_ws[qidx], rl = rl_ws[qidx];

    const int co = g & 7, wh = g >> 3;
    float acc[8][8];
#pragma unroll
    for (int a = 0; a < 8; ++a)
#pragma unroll
        for (int b = 0; b < 8; ++b) acc[a][b] = 0.f;

#pragma unroll 1
    for (int ys = 0; ys < 16; ++ys) {
        const int y0 = ys * 4;
#pragma unroll
        for (int j = 0; j < 4; ++j) {
            const int u  = j * 1024 + tid;
            const int yi = u >> 10;
            const int c  = (u >> 4) & 63;
            const int dv = (u & 15) * 4;
            *reinterpret_cast<float4*>(&Vy[yi][c][dv]) =
                *reinterpret_cast<const float4*>(&V[c * SQC + h * SH + (y0 + yi) * SW + dv]);
        }
        if (tid < 512) {
            const int yi = tid >> 7;
            const int c  = (tid >> 4) & 7;
            const int dv = (tid & 15) * 4;
            *reinterpret_cast<float4*>(&Ky[yi][c][dv]) =
                *reinterpret_cast<const float4*>(&K[c * SQC + h * SH + (y0 + yi) * SW + dv]);
        }
        __syncthreads();

#pragma unroll
        for (int yi = 0; yi < 4; ++yi) {
            float e = 0.f;
#pragma unroll
            for (int c = 0; c < 8; ++c) e = fmaf(q[c], Ky[yi][c][d], e);
            Ay[yi][g][d] = __expf(e - m) * rl;   // no diagonal mask on W
        }
        __syncthreads();

#pragma unroll
        for (int yi = 0; yi < 4; ++yi) {
            float va[8], pa[8];
#pragma unroll
            for (int cc = 0; cc < 8; ++cc) va[cc] = Vy[yi][8 * co + cc][d];
#pragma unroll
            for (int ww = 0; ww < 8; ++ww) pa[ww] = Ay[yi][8 * wh + ww][d];
#pragma unroll
            for (int cc = 0; cc < 8; ++cc)
#pragma unroll
                for (int ww = 0; ww < 8; ++ww)
                    acc[cc][ww] = fmaf(va[cc], pa[ww], acc[cc][ww]);
        }
        __syncthreads();
    }

#pragma unroll
    for (int cc = 0; cc < 8; ++cc)
#pragma unroll
        for (int ww = 0; ww < 8; ++ww) {
            float* op = &out[(8 * co + cc) * SQC + h * SH + (wbase + 8 * wh + ww) * SW + d];
            *op += acc[cc][ww];
        }
}

// ---------------------------------------------------------------------------
extern "C" void kernel_launch(void* const* d_in, const int* in_sizes, int n_in,
                              void* d_out, int out_size, void* d_ws, size_t ws_size,
                              hipStream_t stream)
{
    const float* Q = (const float*)d_in[0];
    const float* K = (const float*)d_in[1];
    const float* V = (const float*)d_in[2];
    float* out = (float*)d_out;

    // ws layout (floats): mH, lH, mW, lW, M, RL  -> 6 MB total
    float* mH = (float*)d_ws;
    float* lH = mH + SQC;
    float* mW = lH + SQC;
    float* lW = mW + SQC;
    float* M  = lW + SQC;
    float* RL = M  + SQC;

    hipLaunchKernelGGL((k_stats_hw<0>), dim3(256), dim3(1024), 0, stream, Q, K, mH, lH);
    hipLaunchKernelGGL((k_stats_hw<1>), dim3(256), dim3(1024), 0, stream, Q, K, mW, lW);
    hipLaunchKernelGGL(k_dpass, dim3(4096), dim3(256), 0, stream, Q, K, V, mH, lH, mW, lW, M, RL, out);
    hipLaunchKernelGGL(k_hpass, dim3(256),  dim3(1024), 0, stream, Q, K, V, M, RL, out);
    hipLaunchKernelGGL(k_wpass, dim3(256),  dim3(1024), 0, stream, Q, K, V, M, RL, out);
}

// Round 10
// 324.749 us; speedup vs baseline: 1.9228x; 1.0845x over previous
//
#include <hip/hip_runtime.h>
#include <math.h>

// Problem constants: B=1, CQ=8, CV=64, H=W=D=64, fp32.
#define SQC 262144   // channel stride = 64*64*64
#define SH  4096     // h stride = 64*64
#define SW  64       // w stride

// ---------------------------------------------------------------------------
// K1a/K1b: per-axis softmax partial stats via LDS-staged streaming K.
// (unchanged from round 5)
// ---------------------------------------------------------------------------
template <int AXIS>
__global__ __launch_bounds__(1024) void k_stats_hw(
    const float* __restrict__ Q, const float* __restrict__ K,
    float* __restrict__ m_out, float* __restrict__ l_out)
{
    __shared__ float Kc[8][8][64];   // [key-in-chunk][c][d]

    const int tid   = threadIdx.x;
    const int d     = tid & 63;
    const int g     = tid >> 6;                 // 0..15
    const int fixed = blockIdx.x & 63;          // w (AXIS=0) or h (AXIS=1)
    const int mbase = (blockIdx.x >> 6) << 4;   // query-tile base on moving axis

    const int MS = (AXIS == 0) ? SH : SW;       // stride of streamed key index
    const int FS = (AXIS == 0) ? SW : SH;       // stride of fixed index

    const int qoff = (AXIS == 0) ? ((mbase + g) * SH + fixed * SW + d)
                                 : (fixed * SH + (mbase + g) * SW + d);
    float q[8];
#pragma unroll
    for (int c = 0; c < 8; ++c) q[c] = Q[c * SQC + qoff];

    float m = -INFINITY, l = 0.f;

#pragma unroll 1
    for (int kc = 0; kc < 8; ++kc) {
#pragma unroll
        for (int j = 0; j < 4; ++j) {
            const int t  = tid + j * 1024;
            const int xi = t >> 9;
            const int c  = (t >> 6) & 7;
            const int dd = t & 63;
            Kc[xi][c][dd] = K[c * SQC + (kc * 8 + xi) * MS + fixed * FS + dd];
        }
        __syncthreads();

        float e[8];
#pragma unroll
        for (int xi = 0; xi < 8; ++xi) {
            float a = 0.f;
#pragma unroll
            for (int c = 0; c < 8; ++c)
                a = fmaf(q[c], Kc[xi][c][d], a);
            if (AXIS == 0 && (kc * 8 + xi) == (mbase + g)) a = -INFINITY;
            e[xi] = a;
        }
        float cm = e[0];
#pragma unroll
        for (int xi = 1; xi < 8; ++xi) cm = fmaxf(cm, e[xi]);
        const float nm = fmaxf(m, cm);
        float s = 0.f;
#pragma unroll
        for (int xi = 0; xi < 8; ++xi) s += __expf(e[xi] - nm);
        l = fmaf(l, __expf(m - nm), s);
        m = nm;
        __syncthreads();
    }

    m_out[qoff] = m;
    l_out[qoff] = l;
}

// ---------------------------------------------------------------------------
// K2: fused D-axis stats + merge + D-axis PV pass. (unchanged from round 8)
// ---------------------------------------------------------------------------
__global__ __launch_bounds__(256) void k_dpass(
    const float* __restrict__ Q, const float* __restrict__ K, const float* __restrict__ V,
    const float* __restrict__ mH, const float* __restrict__ lH,
    const float* __restrict__ mW, const float* __restrict__ lW,
    float* __restrict__ M_out, float* __restrict__ RL_out,
    float* __restrict__ out)
{
    __shared__ float KD[8][64];     // [c][z]
    __shared__ float VDT[64][68];   // [z][c], +4 pad
    __shared__ float AZ[64][64];    // [z][d]
    __shared__ float sm[4][64], sl[4][64], Ms[64], RLs[64];

    const int tid = threadIdx.x;
    const int d   = tid & 63;
    const int zq  = tid >> 6;                 // 0..3
    const int h = blockIdx.x >> 6, w = blockIdx.x & 63;
    const int base = h * SH + w * SW;

    if (tid < 128) {
        const int c = tid >> 4, dv = (tid & 15) * 4;
        *reinterpret_cast<float4*>(&KD[c][dv]) =
            *reinterpret_cast<const float4*>(&K[c * SQC + base + dv]);
    }
#pragma unroll
    for (int j = 0; j < 4; ++j) {
        const int c0 = 16 * zq + 4 * j;
        float4 v;
        v.x = V[(c0 + 0) * SQC + base + d];
        v.y = V[(c0 + 1) * SQC + base + d];
        v.z = V[(c0 + 2) * SQC + base + d];
        v.w = V[(c0 + 3) * SQC + base + d];
        *reinterpret_cast<float4*>(&VDT[d][c0]) = v;
    }

    float q[8];
#pragma unroll
    for (int c = 0; c < 8; ++c) q[c] = Q[c * SQC + base + d];
    __syncthreads();

    float e[16];
#pragma unroll
    for (int zi = 0; zi < 16; ++zi) {
        const int z = zq * 16 + zi;
        float a = 0.f;
#pragma unroll
        for (int c = 0; c < 8; ++c)
            a = fmaf(q[c], KD[c][z], a);
        e[zi] = (z == d) ? -INFINITY : a;
    }
    float pm = e[0];
#pragma unroll
    for (int zi = 1; zi < 16; ++zi) pm = fmaxf(pm, e[zi]);
    float pl = 0.f;
#pragma unroll
    for (int zi = 0; zi < 16; ++zi) pl += __expf(e[zi] - pm);
    sm[zq][d] = pm;
    sl[zq][d] = pl;
    __syncthreads();

    if (tid < 64) {
        const float m0 = sm[0][d], m1 = sm[1][d], m2 = sm[2][d], m3 = sm[3][d];
        const float mD = fmaxf(fmaxf(m0, m1), fmaxf(m2, m3));
        const float lD = sl[0][d] * __expf(m0 - mD) + sl[1][d] * __expf(m1 - mD)
                       + sl[2][d] * __expf(m2 - mD) + sl[3][d] * __expf(m3 - mD);
        const int idx = base + d;
        const float mh = mH[idx], mw = mW[idx];
        const float M  = fmaxf(fmaxf(mh, mw), mD);
        const float L  = lH[idx] * __expf(mh - M) + lW[idx] * __expf(mw - M)
                       + lD * __expf(mD - M);
        const float RL = 1.0f / L;
        M_out[idx]  = M;
        RL_out[idx] = RL;
        Ms[d]  = M;
        RLs[d] = RL;
    }
    __syncthreads();

    {
        const float M = Ms[d], RL = RLs[d];
#pragma unroll
        for (int zi = 0; zi < 16; ++zi) {
            const int z = zq * 16 + zi;
            AZ[z][d] = (z == d) ? 0.f : __expf(e[zi] - M) * RL;
        }
    }
    __syncthreads();

    const int ci = tid >> 4, dj = tid & 15;
    float acc[4][4];
#pragma unroll
    for (int a = 0; a < 4; ++a)
#pragma unroll
        for (int b = 0; b < 4; ++b) acc[a][b] = 0.f;

#pragma unroll 8
    for (int z = 0; z < 64; ++z) {
        const float4 va = *reinterpret_cast<const float4*>(&VDT[z][4 * ci]);
        const float4 vb = *reinterpret_cast<const float4*>(&AZ[z][4 * dj]);
        const float av[4] = {va.x, va.y, va.z, va.w};
        const float bv[4] = {vb.x, vb.y, vb.z, vb.w};
#pragma unroll
        for (int a = 0; a < 4; ++a)
#pragma unroll
            for (int b = 0; b < 4; ++b)
                acc[a][b] = fmaf(av[a], bv[b], acc[a][b]);
    }

#pragma unroll
    for (int a = 0; a < 4; ++a) {
        const float4 o = make_float4(acc[a][0], acc[a][1], acc[a][2], acc[a][3]);
        *reinterpret_cast<float4*>(&out[(4 * ci + a) * SQC + base + 4 * dj]) = o;
    }
}

// ---------------------------------------------------------------------------
// K3: H-axis pass, c-split for 2 blocks/CU.
// Block = (w, 16-h tile, 32-channel half), 1024 thr, 2-x supersteps.
// LDS 28 KB (was 88) and VGPR forced <=64 via __launch_bounds__(1024,8)
// -> 2 blocks/CU co-resident; one block's MAC hides the other's staging.
// Energy (Ax) is computed redundantly in both c-halves (cheap phase).
// ---------------------------------------------------------------------------
__global__ __launch_bounds__(1024, 8) void k_hpass(
    const float* __restrict__ Q, const float* __restrict__ K, const float* __restrict__ V,
    const float* __restrict__ m_ws, const float* __restrict__ rl_ws,
    float* __restrict__ out)
{
    __shared__ float Kx[2][8][64];    // [xi][c][d]
    __shared__ float Vx[2][32][64];   // [xi][c-half][d]
    __shared__ float Ax[2][16][64];   // [xi][h-query][d]

    const int tid = threadIdx.x;
    const int d   = tid & 63;
    const int g   = tid >> 6;                         // 0..15
    const int w     = blockIdx.x & 63;
    const int hbase = ((blockIdx.x >> 6) & 3) << 4;   // 0,16,32,48
    const int c0    = (blockIdx.x >> 8) << 5;         // 0 or 32

    // energy role: query (h_e, w, d)
    const int h_e = hbase + g;
    float q[8];
#pragma unroll
    for (int c = 0; c < 8; ++c) q[c] = Q[c * SQC + h_e * SH + w * SW + d];
    const int qidx = h_e * SH + w * SW + d;
    const float m = m_ws[qidx], rl = rl_ws[qidx];

    // MAC role: c-octet co (0..3 within half), h-quad hg (0..3)
    const int co = g & 3, hg = g >> 2;
    float acc[8][4];
#pragma unroll
    for (int a = 0; a < 8; ++a)
#pragma unroll
        for (int b = 0; b < 4; ++b) acc[a][b] = 0.f;

    // staging indices (constant across supersteps)
    const int sv_xi = tid >> 9;             // 0..1
    const int sv_c  = (tid >> 4) & 31;      // 0..31
    const int sv_dv = (tid & 15) * 4;
    const int sk_xi = tid >> 7;             // for tid<256
    const int sk_c  = (tid >> 4) & 7;

#pragma unroll 1
    for (int ss = 0; ss < 32; ++ss) {
        const int x0 = ss * 2;
        // stage V half-channels: 1024 float4, 1 per thread
        *reinterpret_cast<float4*>(&Vx[sv_xi][sv_c][sv_dv]) =
            *reinterpret_cast<const float4*>(
                &V[(c0 + sv_c) * SQC + (x0 + sv_xi) * SH + w * SW + sv_dv]);
        // stage K: 256 float4
        if (tid < 256) {
            *reinterpret_cast<float4*>(&Kx[sk_xi][sk_c][sv_dv]) =
                *reinterpret_cast<const float4*>(
                    &K[sk_c * SQC + (x0 + sk_xi) * SH + w * SW + sv_dv]);
        }
        __syncthreads();

        // energies for 2 x
#pragma unroll
        for (int xi = 0; xi < 2; ++xi) {
            float e = 0.f;
#pragma unroll
            for (int c = 0; c < 8; ++c) e = fmaf(q[c], Kx[xi][c][d], e);
            Ax[xi][g][d] = ((x0 + xi) == h_e) ? 0.f : __expf(e - m) * rl;
        }
        __syncthreads();

        // MAC over 2 x
#pragma unroll
        for (int xi = 0; xi < 2; ++xi) {
            float va[8], pa[4];
#pragma unroll
            for (int cc = 0; cc < 8; ++cc) va[cc] = Vx[xi][8 * co + cc][d];
#pragma unroll
            for (int aa = 0; aa < 4; ++aa) pa[aa] = Ax[xi][4 * hg + aa][d];
#pragma unroll
            for (int cc = 0; cc < 8; ++cc)
#pragma unroll
                for (int aa = 0; aa < 4; ++aa)
                    acc[cc][aa] = fmaf(va[cc], pa[aa], acc[cc][aa]);
        }
        __syncthreads();
    }

#pragma unroll
    for (int cc = 0; cc < 8; ++cc)
#pragma unroll
        for (int aa = 0; aa < 4; ++aa) {
            float* op = &out[(c0 + 8 * co + cc) * SQC + (hbase + 4 * hg + aa) * SH + w * SW + d];
            *op += acc[cc][aa];
        }
}

// ---------------------------------------------------------------------------
// K4: W-axis pass, c-split, same structure as K3. No mask.
// ---------------------------------------------------------------------------
__global__ __launch_bounds__(1024, 8) void k_wpass(
    const float* __restrict__ Q, const float* __restrict__ K, const float* __restrict__ V,
    const float* __restrict__ m_ws, const float* __restrict__ rl_ws,
    float* __restrict__ out)
{
    __shared__ float Ky[2][8][64];
    __shared__ float Vy[2][32][64];
    __shared__ float Ay[2][16][64];

    const int tid = threadIdx.x;
    const int d   = tid & 63;
    const int g   = tid >> 6;
    const int h     = blockIdx.x & 63;
    const int wbase = ((blockIdx.x >> 6) & 3) << 4;
    const int c0    = (blockIdx.x >> 8) << 5;

    const int w_e = wbase + g;
    float q[8];
#pragma unroll
    for (int c = 0; c < 8; ++c) q[c] = Q[c * SQC + h * SH + w_e * SW + d];
    const int qidx = h * SH + w_e * SW + d;
    const float m = m_ws[qidx], rl = rl_ws[qidx];

    const int co = g & 3, wg = g >> 2;
    float acc[8][4];
#pragma unroll
    for (int a = 0; a < 8; ++a)
#pragma unroll
        for (int b = 0; b < 4; ++b) acc[a][b] = 0.f;

    const int sv_yi = tid >> 9;
    const int sv_c  = (tid >> 4) & 31;
    const int sv_dv = (tid & 15) * 4;
    const int sk_yi = tid >> 7;
    const int sk_c  = (tid >> 4) & 7;

#pragma unroll 1
    for (int ss = 0; ss < 32; ++ss) {
        const int y0 = ss * 2;
        *reinterpret_cast<float4*>(&Vy[sv_yi][sv_c][sv_dv]) =
            *reinterpret_cast<const float4*>(
                &V[(c0 + sv_c) * SQC + h * SH + (y0 + sv_yi) * SW + sv_dv]);
        if (tid < 256) {
            *reinterpret_cast<float4*>(&Ky[sk_yi][sk_c][sv_dv]) =
                *reinterpret_cast<const float4*>(
                    &K[sk_c * SQC + h * SH + (y0 + sk_yi) * SW + sv_dv]);
        }
        __syncthreads();

#pragma unroll
        for (int yi = 0; yi < 2; ++yi) {
            float e = 0.f;
#pragma unroll
            for (int c = 0; c < 8; ++c) e = fmaf(q[c], Ky[yi][c][d], e);
            Ay[yi][g][d] = __expf(e - m) * rl;   // no diagonal mask on W
        }
        __syncthreads();

#pragma unroll
        for (int yi = 0; yi < 2; ++yi) {
            float va[8], pa[4];
#pragma unroll
            for (int cc = 0; cc < 8; ++cc) va[cc] = Vy[yi][8 * co + cc][d];
#pragma unroll
            for (int aa = 0; aa < 4; ++aa) pa[aa] = Ay[yi][4 * wg + aa][d];
#pragma unroll
            for (int cc = 0; cc < 8; ++cc)
#pragma unroll
                for (int aa = 0; aa < 4; ++aa)
                    acc[cc][aa] = fmaf(va[cc], pa[aa], acc[cc][aa]);
        }
        __syncthreads();
    }

#pragma unroll
    for (int cc = 0; cc < 8; ++cc)
#pragma unroll
        for (int aa = 0; aa < 4; ++aa) {
            float* op = &out[(c0 + 8 * co + cc) * SQC + h * SH + (wbase + 4 * wg + aa) * SW + d];
            *op += acc[cc][aa];
        }
}

// ---------------------------------------------------------------------------
extern "C" void kernel_launch(void* const* d_in, const int* in_sizes, int n_in,
                              void* d_out, int out_size, void* d_ws, size_t ws_size,
                              hipStream_t stream)
{
    const float* Q = (const float*)d_in[0];
    const float* K = (const float*)d_in[1];
    const float* V = (const float*)d_in[2];
    float* out = (float*)d_out;

    // ws layout (floats): mH, lH, mW, lW, M, RL  -> 6 MB total
    float* mH = (float*)d_ws;
    float* lH = mH + SQC;
    float* mW = lH + SQC;
    float* lW = mW + SQC;
    float* M  = lW + SQC;
    float* RL = M  + SQC;

    hipLaunchKernelGGL((k_stats_hw<0>), dim3(256), dim3(1024), 0, stream, Q, K, mH, lH);
    hipLaunchKernelGGL((k_stats_hw<1>), dim3(256), dim3(1024), 0, stream, Q, K, mW, lW);
    hipLaunchKernelGGL(k_dpass, dim3(4096), dim3(256), 0, stream, Q, K, V, mH, lH, mW, lW, M, RL, out);
    hipLaunchKernelGGL(k_hpass, dim3(512),  dim3(1024), 0, stream, Q, K, V, M, RL, out);
    hipLaunchKernelGGL(k_wpass, dim3(512),  dim3(1024), 0, stream, Q, K, V, M, RL, out);
}